// Round 2
// baseline (767.162 us; speedup 1.0000x reference)
//
#include <hip/hip_runtime.h>
#include <stdint.h>
#include <stddef.h>

// MaskedLinear: y = x @ W.T + b, rows zeroed where amask==0.
// N=1e6, IN=OUT=128, fp32 in/out. bf16 MFMA compute (2% absmax budget).
//
// Strategy: memory-bound streaming GEMM. Each wave holds all of W (bf16
// B-fragments, 128 VGPRs) + bias in registers, grid-strides over 16-row
// tiles. x A-fragments load straight from global (row-contiguous matches
// A[m=lane&15][k=(lane>>4)*8+j]); loads predicated on mask to halve x read
// traffic. C/D layout (verified m89): col=lane&15, row=(lane>>4)*4+reg.
//
// R2 fix: amask is a 4-byte-per-element buffer (harness converts bool to an
// integer/float type). Read as int32 words, test word != 0 — correct for
// both int32 {0,1} and float32 {0.0f,1.0f} encodings. R1's byte-wise read
// zeroed ~87.5% of rows (absmax == max|ref| signature).

typedef __attribute__((ext_vector_type(8))) short short8;   // 8 bf16 = 4 VGPRs
typedef __attribute__((ext_vector_type(4))) float f32x4;    // MFMA acc

__device__ __forceinline__ unsigned short f2bf(float f) {
    union { float f; unsigned int u; } v; v.f = f;
    unsigned int u = v.u;
    // round-to-nearest-even
    unsigned int r = (u + 0x7FFFu + ((u >> 16) & 1u)) >> 16;
    return (unsigned short)r;
}

__device__ __forceinline__ short8 pack8(float4 lo, float4 hi) {
    short8 r;
    r[0] = (short)f2bf(lo.x); r[1] = (short)f2bf(lo.y);
    r[2] = (short)f2bf(lo.z); r[3] = (short)f2bf(lo.w);
    r[4] = (short)f2bf(hi.x); r[5] = (short)f2bf(hi.y);
    r[6] = (short)f2bf(hi.z); r[7] = (short)f2bf(hi.w);
    return r;
}

__global__ __launch_bounds__(256, 2)
void masked_linear_kernel(const float* __restrict__ x,
                          const int* __restrict__ amask,
                          const float* __restrict__ W,
                          const float* __restrict__ bias,
                          float* __restrict__ out,
                          int n_tiles, int n_waves)
{
    const int lane = threadIdx.x & 63;
    const int wid  = blockIdx.x * (blockDim.x >> 6) + (threadIdx.x >> 6);
    const int ln   = lane & 15;   // m (A row) / n (B col) / C col index
    const int kg   = lane >> 4;   // k-group (0..3)

    // ---- W as bf16 B-fragments in registers, bias per col-tile ----
    // B[k][n] = W.T[k][n] = W[n][k]; lane holds n=t*16+ln, k=s*32+kg*8+j
    short8 wf[8][4];
    float  bv[8];
#pragma unroll
    for (int t = 0; t < 8; ++t) {
        bv[t] = bias[t * 16 + ln];
        const float* wr = W + (t * 16 + ln) * 128 + kg * 8;
#pragma unroll
        for (int s = 0; s < 4; ++s) {
            const float4* p = reinterpret_cast<const float4*>(wr + s * 32);
            wf[t][s] = pack8(p[0], p[1]);
        }
    }

    for (int tile = wid; tile < n_tiles; tile += n_waves) {
        const int r0   = tile << 4;
        const int arow = r0 + ln;                 // row this lane loads (A frag)
        const bool m   = amask[arow] != 0;        // 4-byte word test
        // store rows for this lane: r0 + kg*4 + {0..3}; 4 int32 words, aligned
        const int4 smask =
            *reinterpret_cast<const int4*>(amask + r0 + (kg << 2));

        // ---- A fragments: predicated direct-from-global loads ----
        const float* xr = x + (size_t)arow * 128 + kg * 8;
        short8 a[4];
#pragma unroll
        for (int s = 0; s < 4; ++s) {
            float4 lo = make_float4(0.f, 0.f, 0.f, 0.f);
            float4 hi = make_float4(0.f, 0.f, 0.f, 0.f);
            if (m) {
                const float4* p = reinterpret_cast<const float4*>(xr + s * 32);
                lo = p[0]; hi = p[1];
            }
            a[s] = pack8(lo, hi);
        }

        // ---- acc init with bias (same col for all 4 regs) ----
        f32x4 acc[8];
#pragma unroll
        for (int t = 0; t < 8; ++t) {
            f32x4 v = {bv[t], bv[t], bv[t], bv[t]};
            acc[t] = v;
        }
#pragma unroll
        for (int s = 0; s < 4; ++s)
#pragma unroll
            for (int t = 0; t < 8; ++t)
                acc[t] = __builtin_amdgcn_mfma_f32_16x16x32_bf16(
                             a[s], wf[t][s], acc[t], 0, 0, 0);

        // ---- store: row=(lane>>4)*4+r, col=t*16+ln; zero masked-out rows ----
        float* orow = out + (size_t)(r0 + (kg << 2)) * 128 + ln;
        const int km[4] = {smask.x, smask.y, smask.z, smask.w};
#pragma unroll
        for (int r = 0; r < 4; ++r) {
            const bool keep = km[r] != 0;
            float* op = orow + r * 128;
#pragma unroll
            for (int t = 0; t < 8; ++t)
                op[t * 16] = keep ? acc[t][r] : 0.0f;
        }
    }
}

extern "C" void kernel_launch(void* const* d_in, const int* in_sizes, int n_in,
                              void* d_out, int out_size, void* d_ws, size_t ws_size,
                              hipStream_t stream) {
    const float* x     = (const float*)d_in[0];
    const int*   amask = (const int*)d_in[1];
    const float* W     = (const float*)d_in[2];
    const float* b     = (const float*)d_in[3];
    float*       out   = (float*)d_out;

    const int n_rows  = in_sizes[1];      // 1,000,000 (multiple of 16)
    const int n_tiles = n_rows >> 4;      // 62,500
    const int blocks  = 512;              // 2048 waves ~= fully resident
    const int n_waves = blocks * 4;

    hipLaunchKernelGGL(masked_linear_kernel, dim3(blocks), dim3(256), 0, stream,
                       x, amask, W, b, out, n_tiles, n_waves);
}